// Round 2
// baseline (2508.322 us; speedup 1.0000x reference)
//
#include <hip/hip_runtime.h>
#include <hip/hip_bf16.h>

#define F 32
#define BN_EPS 1e-5f

typedef __hip_bfloat16 bf16;

// Dual-dtype input loader: isbf chosen at runtime by detect_k. Indexes ELEMENTS.
__device__ __forceinline__ float ldin(const void* p, int i, int isbf) {
    if (isbf) return __bfloat162float(((const bf16*)p)[i]);
    return ((const float*)p)[i];
}

// fp32 N(0,1) words: exponent field <= ~130. bf16 pairs viewed as fp32 words:
// the high bf16's exponent bits land in the exponent field -> >= 240 almost always.
__global__ void detect_k(const unsigned* __restrict__ xw, int nw, int* __restrict__ flag) {
    __shared__ int cnt;
    if (threadIdx.x == 0) cnt = 0;
    __syncthreads();
    int hits = 0;
    for (int i = threadIdx.x; i < nw; i += 256) {
        unsigned e = (xw[i] >> 23) & 0xFF;
        if (e >= 0xF0) hits++;
    }
    atomicAdd(&cnt, hits);
    __syncthreads();
    if (threadIdx.x == 0) *flag = (cnt > nw / 2) ? 1 : 0;
}

__global__ __launch_bounds__(256) void spmm_in_k(const void* __restrict__ z,
                                                 const int* __restrict__ src,
                                                 const int* __restrict__ dst,
                                                 float* __restrict__ out, int ne,
                                                 const int* __restrict__ flag) {
    int isbf = *flag;
    int t = blockIdx.x * 256 + threadIdx.x;
    int e = t >> 5;
    if (e >= ne) return;
    int f = t & 31;
    atomicAdd(&out[dst[e] * F + f], ldin(z, src[e] * F + f, isbf));
}

__global__ __launch_bounds__(256) void spmm_f32_k(const float* __restrict__ z,
                                                  const int* __restrict__ src,
                                                  const int* __restrict__ dst,
                                                  float* __restrict__ out, int ne) {
    int t = blockIdx.x * 256 + threadIdx.x;
    int e = t >> 5;
    if (e >= ne) return;
    int f = t & 31;
    atomicAdd(&out[dst[e] * F + f], z[src[e] * F + f]);
}

__global__ __launch_bounds__(256) void scatter_edges_k(const void* __restrict__ y,
                                                       const int* __restrict__ dst,
                                                       float* __restrict__ out, int ne,
                                                       const int* __restrict__ flag) {
    int isbf = *flag;
    int t = blockIdx.x * 256 + threadIdx.x;
    int e = t >> 5;
    if (e >= ne) return;
    int f = t & 31;
    atomicAdd(&out[dst[e] * F + f], ldin(y, e * F + f, isbf));
}

// acc = in0@W0^T + deg*(in0@W1^T) + aux@W2^T + (main biases + list biases)
__global__ __launch_bounds__(256) void main_linear_k(
    const void* __restrict__ in0, const void* __restrict__ deg,
    const float* __restrict__ aux32, const void* __restrict__ auxsrc,
    const int* __restrict__ auxidx,
    const void* __restrict__ Wm, const void* __restrict__ bm,
    const void* __restrict__ bl,
    float* __restrict__ acc, int R, const int* __restrict__ flag)
{
    int isbf = *flag;
    __shared__ float Wt[3][F][F + 1];  // Wt[m][k][f] = W[m][f][k]
    __shared__ float srow[8][F];
    __shared__ float arow[8][F];
    __shared__ float sdeg[8];

    int tid = threadIdx.x;
    for (int i = tid; i < 3 * F * F; i += 256) {
        int m = i >> 10, r = (i >> 5) & 31, k = i & 31;
        Wt[m][k][r] = ldin(Wm, i, isbf);
    }
    int f = tid & 31, lr = tid >> 5;
    int row = blockIdx.x * 8 + lr;
    bool valid = row < R;
    if (valid) {
        srow[lr][f] = ldin(in0, row * F + f, isbf);
        if (aux32) arow[lr][f] = aux32[row * F + f];
        else       arow[lr][f] = ldin(auxsrc, auxidx[row] * F + f, isbf);
        if (f == 0) sdeg[lr] = ldin(deg, row, isbf);
    }
    __syncthreads();
    if (!valid) return;
    float a0 = 0.f, a1 = 0.f, a2 = 0.f;
#pragma unroll
    for (int k = 0; k < F; k++) {
        float xv = srow[lr][k];
        a0 += xv * Wt[0][k][f];
        a1 += xv * Wt[1][k][f];
        a2 += arow[lr][k] * Wt[2][k][f];
    }
    float bt = ldin(bm, f, isbf) + ldin(bm, F + f, isbf) + ldin(bm, 2 * F + f, isbf)
             + ldin(bl, f, isbf) + ldin(bl, F + f, isbf) + ldin(bl, 2 * F + f, isbf);
    acc[row * F + f] = a0 + sdeg[lr] * a1 + a2 + bt;
}

// acc += z @ W^T, W at element offset woff in a [RADIUS,32,32] tensor
__global__ __launch_bounds__(256) void accum_linear_k(const float* __restrict__ z,
                                                      const void* __restrict__ W, int woff,
                                                      float* __restrict__ acc, int R,
                                                      const int* __restrict__ flag) {
    int isbf = *flag;
    __shared__ float Wt[F][F + 1];
    __shared__ float srow[8][F];
    int tid = threadIdx.x;
    for (int i = tid; i < F * F; i += 256) {
        int r = i >> 5, k = i & 31;
        Wt[k][r] = ldin(W, woff + i, isbf);
    }
    int f = tid & 31, lr = tid >> 5;
    int row = blockIdx.x * 8 + lr;
    if (row < R) srow[lr][f] = z[row * F + f];
    __syncthreads();
    if (row >= R) return;
    float a = 0.f;
#pragma unroll
    for (int k = 0; k < F; k++) a += srow[lr][k] * Wt[k][f];
    acc[row * F + f] += a;
}

__global__ __launch_bounds__(256) void stats_relu_k(float* __restrict__ acc, int R,
                                                    float* __restrict__ stats) {
    int total = R * F;
    int stride = gridDim.x * 256;
    float s = 0.f, ss = 0.f;
    for (int i = blockIdx.x * 256 + threadIdx.x; i < total; i += stride) {
        float v = acc[i];
        if ((i & 31) >= 16) v = fmaxf(v, 0.f);
        acc[i] = v;
        s += v;
        ss += v * v;
    }
    __shared__ float Ss[256], Sq[256];
    Ss[threadIdx.x] = s; Sq[threadIdx.x] = ss;
    __syncthreads();
    for (int off = 128; off >= 32; off >>= 1) {
        if (threadIdx.x < off) {
            Ss[threadIdx.x] += Ss[threadIdx.x + off];
            Sq[threadIdx.x] += Sq[threadIdx.x + off];
        }
        __syncthreads();
    }
    if (threadIdx.x < 32) {
        atomicAdd(&stats[threadIdx.x], Ss[threadIdx.x]);
        atomicAdd(&stats[32 + threadIdx.x], Sq[threadIdx.x]);
    }
}

__global__ void scalebias_k(const float* __restrict__ stats,
                            const void* __restrict__ sc_x, const void* __restrict__ bi_x,
                            const void* __restrict__ sc_y, const void* __restrict__ bi_y,
                            float* __restrict__ sb, int Rx, int Ry,
                            const int* __restrict__ flag) {
    int isbf = *flag;
    int tid = threadIdx.x;  // 64 threads
    if (tid >= 64) return;
    int side = tid >> 5, f = tid & 31;
    const float* st = stats + side * 64;
    float Rn = side ? (float)Ry : (float)Rx;
    float mean = st[f] / Rn;
    float var = st[32 + f] / Rn - mean * mean;
    float a = rsqrtf(var + BN_EPS) * ldin(side ? sc_y : sc_x, f, isbf);
    float b = ldin(side ? bi_y : bi_x, f, isbf) - mean * a;
    sb[side * 64 + f] = a;
    sb[side * 64 + 32 + f] = b;
}

// normalize + store at ELEMENT offset ooff into out (dtype-dependent size handled here)
__global__ __launch_bounds__(256) void finalize_k(const float* __restrict__ acc,
                                                  const float* __restrict__ sb,
                                                  void* __restrict__ out, int ooff, int R,
                                                  const int* __restrict__ flag) {
    int isbf = *flag;
    int i = blockIdx.x * 256 + threadIdx.x;
    if (i >= R * F) return;
    int f = i & 31;
    float v = acc[i] * sb[f] + sb[32 + f];
    if (isbf) ((bf16*)out)[ooff + i] = __float2bfloat16(v);
    else      ((float*)out)[ooff + i] = v;
}

extern "C" void kernel_launch(void* const* d_in, const int* in_sizes, int n_in,
                              void* d_out, int out_size, void* d_ws, size_t ws_size,
                              hipStream_t stream) {
    const void* x       = d_in[0];
    const void* y       = d_in[1];
    const void* deg_g   = d_in[2];
    const void* deg_lg  = d_in[3];
    const void* th_mw   = d_in[4];
    const void* th_mb   = d_in[5];
    const void* th_lw   = d_in[6];
    const void* th_lb   = d_in[7];
    const void* ga_mw   = d_in[8];
    const void* ga_mb   = d_in[9];
    const void* ga_lw   = d_in[10];
    const void* ga_lb   = d_in[11];
    const void* bn_x_sc = d_in[12];
    const void* bn_x_bi = d_in[13];
    const void* bn_y_sc = d_in[14];
    const void* bn_y_bi = d_in[15];
    const int*  g_src   = (const int*)d_in[16];
    const int*  g_dst   = (const int*)d_in[17];
    const int*  lg_src  = (const int*)d_in[18];
    const int*  lg_dst  = (const int*)d_in[19];
    const int*  pm_pd   = (const int*)d_in[20];

    const int N  = in_sizes[0] / F;
    const int E  = in_sizes[1] / F;
    const int LE = in_sizes[18];

    int*   dflag = (int*)d_ws;
    float* stats = (float*)d_ws + 64;
    float* sb    = stats + 128;
    float* zA_x  = sb + 128;
    float* zB_x  = zA_x + (size_t)N * F;
    float* acc_x = zB_x + (size_t)N * F;
    float* pmpd  = acc_x + (size_t)N * F;
    float* zA_y  = pmpd + (size_t)N * F;
    float* zB_y  = zA_y + (size_t)E * F;
    float* acc_y = zB_y + (size_t)E * F;

    const size_t NB = (size_t)N * F * sizeof(float);
    const size_t EB = (size_t)E * F * sizeof(float);
    const int eg = (E * F + 255) / 256;
    const int lg = (LE * F + 255) / 256;
    const int nrx = (N + 7) / 8;
    const int nry = (E + 7) / 8;

    detect_k<<<1, 256, 0, stream>>>((const unsigned*)x, 4096, dflag);

    hipMemsetAsync(stats, 0, 128 * sizeof(float), stream);
    hipMemsetAsync(pmpd, 0, NB, stream);
    hipMemsetAsync(zA_x, 0, NB, stream);
    hipMemsetAsync(zA_y, 0, EB, stream);

    // ---------- x side ----------
    scatter_edges_k<<<eg, 256, 0, stream>>>(y, g_dst, pmpd, E, dflag);
    main_linear_k<<<nrx, 256, 0, stream>>>(x, deg_g, pmpd, nullptr, nullptr,
                                           th_mw, th_mb, th_lb, acc_x, N, dflag);
    spmm_in_k<<<eg, 256, 0, stream>>>(x, g_src, g_dst, zA_x, E, dflag);            // h1
    accum_linear_k<<<nrx, 256, 0, stream>>>(zA_x, th_lw, 0, acc_x, N, dflag);
    hipMemsetAsync(zB_x, 0, NB, stream);
    spmm_f32_k<<<eg, 256, 0, stream>>>(zA_x, g_src, g_dst, zB_x, E);               // h2
    accum_linear_k<<<nrx, 256, 0, stream>>>(zB_x, th_lw, 1024, acc_x, N, dflag);
    hipMemsetAsync(zA_x, 0, NB, stream);
    spmm_f32_k<<<eg, 256, 0, stream>>>(zB_x, g_src, g_dst, zA_x, E);               // h3
    hipMemsetAsync(zB_x, 0, NB, stream);
    spmm_f32_k<<<eg, 256, 0, stream>>>(zA_x, g_src, g_dst, zB_x, E);               // h4
    accum_linear_k<<<nrx, 256, 0, stream>>>(zB_x, th_lw, 2048, acc_x, N, dflag);
    stats_relu_k<<<512, 256, 0, stream>>>(acc_x, N, stats);

    // ---------- y side ----------
    main_linear_k<<<nry, 256, 0, stream>>>(y, deg_lg, nullptr, x, pm_pd,
                                           ga_mw, ga_mb, ga_lb, acc_y, E, dflag);
    spmm_in_k<<<lg, 256, 0, stream>>>(y, lg_src, lg_dst, zA_y, LE, dflag);         // h1
    accum_linear_k<<<nry, 256, 0, stream>>>(zA_y, ga_lw, 0, acc_y, E, dflag);
    hipMemsetAsync(zB_y, 0, EB, stream);
    spmm_f32_k<<<lg, 256, 0, stream>>>(zA_y, lg_src, lg_dst, zB_y, LE);            // h2
    accum_linear_k<<<nry, 256, 0, stream>>>(zB_y, ga_lw, 1024, acc_y, E, dflag);
    hipMemsetAsync(zA_y, 0, EB, stream);
    spmm_f32_k<<<lg, 256, 0, stream>>>(zB_y, lg_src, lg_dst, zA_y, LE);            // h3
    hipMemsetAsync(zB_y, 0, EB, stream);
    spmm_f32_k<<<lg, 256, 0, stream>>>(zA_y, lg_src, lg_dst, zB_y, LE);            // h4
    accum_linear_k<<<nry, 256, 0, stream>>>(zB_y, ga_lw, 2048, acc_y, E, dflag);
    stats_relu_k<<<1024, 256, 0, stream>>>(acc_y, E, stats + 64);

    // ---------- BN fold + write ----------
    scalebias_k<<<1, 64, 0, stream>>>(stats, bn_x_sc, bn_x_bi, bn_y_sc, bn_y_bi,
                                      sb, N, E, dflag);
    finalize_k<<<(N * F + 255) / 256, 256, 0, stream>>>(acc_x, sb, d_out, 0, N, dflag);
    finalize_k<<<(E * F + 255) / 256, 256, 0, stream>>>(acc_y, sb + 64, d_out,
                                                        N * F, E, dflag);
}

// Round 4
// 2224.415 us; speedup vs baseline: 1.1276x; 1.1276x over previous
//
#include <hip/hip_runtime.h>
#include <hip/hip_bf16.h>

#define F 32
#define BN_EPS 1e-5f

// All float tensors are fp32 (verified round 2: FETCH/WRITE_SIZE match fp32 widths;
// bf16 interpretation NaN'd in rounds 1/3). Indices are int32.

// ---------------- one-time weight prep: transpose + interleave + fuse biases ---------
// Wp layout (floats):
//   [0,4096)      WintX[k][f][{m0,m1,m2,pad}]   (theta_main, transposed+interleaved)
//   [4096,7168)   WlX[i][k][f]                  (theta_list, transposed)
//   [7168,7200)   btX[f] = sum_m(theta_main_b) + sum_i(theta_list_b)
//   [7200,11296)  WintY, [11296,14368) WlY, [14368,14400) btY
__global__ void prep_k(const float* __restrict__ th_mw, const float* __restrict__ th_mb,
                       const float* __restrict__ th_lw, const float* __restrict__ th_lb,
                       const float* __restrict__ ga_mw, const float* __restrict__ ga_mb,
                       const float* __restrict__ ga_lw, const float* __restrict__ ga_lb,
                       float* __restrict__ Wp) {
    int gs = gridDim.x * blockDim.x;
    int g0 = blockIdx.x * blockDim.x + threadIdx.x;
    float* WintX = Wp;
    float* WlX   = Wp + 4096;
    float* btX   = Wp + 7168;
    float* WintY = Wp + 7200;
    float* WlY   = Wp + 11296;
    float* btY   = Wp + 14368;
    for (int j = g0; j < 1024; j += gs) {
        int k = j >> 5, f = j & 31;
        for (int m = 0; m < 3; m++) {
            WintX[j * 4 + m] = th_mw[m * 1024 + f * 32 + k];
            WintY[j * 4 + m] = ga_mw[m * 1024 + f * 32 + k];
        }
        WintX[j * 4 + 3] = 0.f;
        WintY[j * 4 + 3] = 0.f;
    }
    for (int j = g0; j < 3072; j += gs) {
        int i = j >> 10, k = (j >> 5) & 31, f = j & 31;
        WlX[j] = th_lw[i * 1024 + f * 32 + k];
        WlY[j] = ga_lw[i * 1024 + f * 32 + k];
    }
    for (int f = g0; f < 32; f += gs) {
        float bx = 0.f, by = 0.f;
        for (int m = 0; m < 3; m++) {
            bx += th_mb[m * 32 + f] + th_lb[m * 32 + f];
            by += ga_mb[m * 32 + f] + ga_lb[m * 32 + f];
        }
        btX[f] = bx;
        btY[f] = by;
    }
}

// ---------------- SPMM (push / atomic): out[dst[e]][f] += z[src[e]][f] ----------------
__global__ __launch_bounds__(256) void spmm_f32_k(const float* __restrict__ z,
                                                  const int* __restrict__ src,
                                                  const int* __restrict__ dst,
                                                  float* __restrict__ out, int ne) {
    int t = blockIdx.x * 256 + threadIdx.x;
    int e = t >> 5;
    if (e >= ne) return;
    int f = t & 31;
    atomicAdd(&out[dst[e] * F + f], z[src[e] * F + f]);
}

// ---------------- segment_sum(y, g_dst) ----------------
__global__ __launch_bounds__(256) void scatter_edges_k(const float* __restrict__ y,
                                                       const int* __restrict__ dst,
                                                       float* __restrict__ out, int ne) {
    int t = blockIdx.x * 256 + threadIdx.x;
    int e = t >> 5;
    if (e >= ne) return;
    int f = t & 31;
    atomicAdd(&out[dst[e] * F + f], y[e * F + f]);
}

// ---------------- main linear, 32 rows/block, transposed LDS tiles ----------------
// acc = in0@W0^T + deg*(in0@W1^T) + aux@W2^T + fused biases
__global__ __launch_bounds__(256) void main_linear_k(
    const float* __restrict__ in0, const float* __restrict__ deg,
    const float* __restrict__ aux32, const float* __restrict__ auxsrc,
    const int* __restrict__ auxidx,
    const float* __restrict__ Wint_g, const float* __restrict__ bt,
    float* __restrict__ acc, int R)
{
    __shared__ float Wint[4096];       // [(k*32+f)*4 + m]
    __shared__ float srow_t[32 * 36];  // [k][r], pad 36
    __shared__ float arow_t[32 * 36];
    __shared__ float sdeg[32];

    int tid = threadIdx.x;
    {
        const float4* g4 = (const float4*)Wint_g;
        float4* s4 = (float4*)Wint;
#pragma unroll
        for (int i = 0; i < 4; i++) s4[tid + i * 256] = g4[tid + i * 256];
    }
    int base = blockIdx.x * 32;
    int r = tid >> 3;             // row within tile this thread loads
    int c = (tid & 7) * 4;        // starting col (16B aligned)
    int row = base + r;
    float4 sv = make_float4(0.f, 0.f, 0.f, 0.f);
    float4 av = make_float4(0.f, 0.f, 0.f, 0.f);
    if (row < R) {
        sv = *(const float4*)(in0 + row * F + c);
        if (aux32) av = *(const float4*)(aux32 + row * F + c);
        else       av = *(const float4*)(auxsrc + auxidx[row] * F + c);
    }
    srow_t[(c + 0) * 36 + r] = sv.x;
    srow_t[(c + 1) * 36 + r] = sv.y;
    srow_t[(c + 2) * 36 + r] = sv.z;
    srow_t[(c + 3) * 36 + r] = sv.w;
    arow_t[(c + 0) * 36 + r] = av.x;
    arow_t[(c + 1) * 36 + r] = av.y;
    arow_t[(c + 2) * 36 + r] = av.z;
    arow_t[(c + 3) * 36 + r] = av.w;
    if (tid < 32) sdeg[tid] = (base + tid < R) ? deg[base + tid] : 0.f;
    __syncthreads();

    int f = tid & 31, lr = tid >> 5;
    int r0 = lr * 4;
    float a0[4] = {0.f, 0.f, 0.f, 0.f};
    float a1[4] = {0.f, 0.f, 0.f, 0.f};
    float a2[4] = {0.f, 0.f, 0.f, 0.f};
    const float4* W4 = (const float4*)Wint;
#pragma unroll
    for (int k = 0; k < 32; k++) {
        float4 w = W4[k * 32 + f];
        float4 s = *(const float4*)(srow_t + k * 36 + r0);
        float4 a = *(const float4*)(arow_t + k * 36 + r0);
        a0[0] = fmaf(s.x, w.x, a0[0]); a1[0] = fmaf(s.x, w.y, a1[0]); a2[0] = fmaf(a.x, w.z, a2[0]);
        a0[1] = fmaf(s.y, w.x, a0[1]); a1[1] = fmaf(s.y, w.y, a1[1]); a2[1] = fmaf(a.y, w.z, a2[1]);
        a0[2] = fmaf(s.z, w.x, a0[2]); a1[2] = fmaf(s.z, w.y, a1[2]); a2[2] = fmaf(a.z, w.z, a2[2]);
        a0[3] = fmaf(s.w, w.x, a0[3]); a1[3] = fmaf(s.w, w.y, a1[3]); a2[3] = fmaf(a.w, w.z, a2[3]);
    }
    float btf = bt[f];
#pragma unroll
    for (int j = 0; j < 4; j++) {
        int rr = base + r0 + j;
        if (rr < R) acc[rr * F + f] = a0[j] + sdeg[r0 + j] * a1[j] + a2[j] + btf;
    }
}

// ---------------- acc += z @ W^T, 32 rows/block ----------------
__global__ __launch_bounds__(256) void accum_linear_k(const float* __restrict__ z,
                                                      const float* __restrict__ Wl, // fp32 [k][f]
                                                      float* __restrict__ acc, int R) {
    __shared__ float Wt[1024];
    __shared__ float zt[32 * 36];
    int tid = threadIdx.x;
    ((float4*)Wt)[tid] = ((const float4*)Wl)[tid];
    int base = blockIdx.x * 32;
    int r = tid >> 3;
    int c = (tid & 7) * 4;
    int row = base + r;
    float4 v = make_float4(0.f, 0.f, 0.f, 0.f);
    if (row < R) v = *(const float4*)(z + row * F + c);
    zt[(c + 0) * 36 + r] = v.x;
    zt[(c + 1) * 36 + r] = v.y;
    zt[(c + 2) * 36 + r] = v.z;
    zt[(c + 3) * 36 + r] = v.w;
    __syncthreads();

    int f = tid & 31, lr = tid >> 5;
    int r0 = lr * 4;
    float a[4] = {0.f, 0.f, 0.f, 0.f};
#pragma unroll
    for (int k = 0; k < 32; k++) {
        float w = Wt[k * 32 + f];
        float4 s = *(const float4*)(zt + k * 36 + r0);
        a[0] = fmaf(s.x, w, a[0]);
        a[1] = fmaf(s.y, w, a[1]);
        a[2] = fmaf(s.z, w, a[2]);
        a[3] = fmaf(s.w, w, a[3]);
    }
#pragma unroll
    for (int j = 0; j < 4; j++) {
        int rr = base + r0 + j;
        if (rr < R) acc[rr * F + f] += a[j];
    }
}

// ---------------- in-place half-ReLU + per-column sum/sumsq ----------------
__global__ __launch_bounds__(256) void stats_relu_k(float* __restrict__ acc, int R,
                                                    float* __restrict__ stats) {
    int total = R * F;
    int stride = gridDim.x * 256;
    float s = 0.f, ss = 0.f;
    for (int i = blockIdx.x * 256 + threadIdx.x; i < total; i += stride) {
        float v = acc[i];
        if ((i & 31) >= 16) v = fmaxf(v, 0.f);
        acc[i] = v;
        s += v;
        ss += v * v;
    }
    __shared__ float Ss[256], Sq[256];
    Ss[threadIdx.x] = s; Sq[threadIdx.x] = ss;
    __syncthreads();
    for (int off = 128; off >= 32; off >>= 1) {
        if (threadIdx.x < off) {
            Ss[threadIdx.x] += Ss[threadIdx.x + off];
            Sq[threadIdx.x] += Sq[threadIdx.x + off];
        }
        __syncthreads();
    }
    if (threadIdx.x < 32) {
        atomicAdd(&stats[threadIdx.x], Ss[threadIdx.x]);
        atomicAdd(&stats[32 + threadIdx.x], Sq[threadIdx.x]);
    }
}

__global__ void scalebias_k(const float* __restrict__ stats,
                            const float* __restrict__ sc_x, const float* __restrict__ bi_x,
                            const float* __restrict__ sc_y, const float* __restrict__ bi_y,
                            float* __restrict__ sb, int Rx, int Ry) {
    int tid = threadIdx.x;  // 64 threads
    if (tid >= 64) return;
    int side = tid >> 5, f = tid & 31;
    const float* st = stats + side * 64;
    float Rn = side ? (float)Ry : (float)Rx;
    float mean = st[f] / Rn;
    float var = st[32 + f] / Rn - mean * mean;
    float a = rsqrtf(var + BN_EPS) * (side ? sc_y[f] : sc_x[f]);
    float b = (side ? bi_y[f] : bi_x[f]) - mean * a;
    sb[side * 64 + f] = a;
    sb[side * 64 + 32 + f] = b;
}

__global__ __launch_bounds__(256) void finalize_k(const float* __restrict__ acc,
                                                  const float* __restrict__ sb,
                                                  float* __restrict__ out, int R) {
    int i = blockIdx.x * 256 + threadIdx.x;
    if (i >= R * F) return;
    int f = i & 31;
    out[i] = acc[i] * sb[f] + sb[32 + f];
}

extern "C" void kernel_launch(void* const* d_in, const int* in_sizes, int n_in,
                              void* d_out, int out_size, void* d_ws, size_t ws_size,
                              hipStream_t stream) {
    const float* x       = (const float*)d_in[0];
    const float* y       = (const float*)d_in[1];
    const float* deg_g   = (const float*)d_in[2];
    const float* deg_lg  = (const float*)d_in[3];
    const float* th_mw   = (const float*)d_in[4];
    const float* th_mb   = (const float*)d_in[5];
    const float* th_lw   = (const float*)d_in[6];
    const float* th_lb   = (const float*)d_in[7];
    const float* ga_mw   = (const float*)d_in[8];
    const float* ga_mb   = (const float*)d_in[9];
    const float* ga_lw   = (const float*)d_in[10];
    const float* ga_lb   = (const float*)d_in[11];
    const float* bn_x_sc = (const float*)d_in[12];
    const float* bn_x_bi = (const float*)d_in[13];
    const float* bn_y_sc = (const float*)d_in[14];
    const float* bn_y_bi = (const float*)d_in[15];
    const int*   g_src   = (const int*)d_in[16];
    const int*   g_dst   = (const int*)d_in[17];
    const int*   lg_src  = (const int*)d_in[18];
    const int*   lg_dst  = (const int*)d_in[19];
    const int*   pm_pd   = (const int*)d_in[20];
    float* out = (float*)d_out;

    const int N  = in_sizes[0] / F;
    const int E  = in_sizes[1] / F;
    const int LE = in_sizes[18];

    float* ws    = (float*)d_ws;
    float* stats = ws;            // 128
    float* sb    = ws + 128;      // 128
    float* Wp    = ws + 256;      // 14400 prepped weights
    float* zA_x  = ws + 256 + 14400;
    float* zB_x  = zA_x + (size_t)N * F;
    float* acc_x = zB_x + (size_t)N * F;
    float* pmpd  = acc_x + (size_t)N * F;
    float* zA_y  = pmpd + (size_t)N * F;
    float* zB_y  = zA_y + (size_t)E * F;
    float* acc_y = zB_y + (size_t)E * F;

    const float* WintX = Wp;
    const float* WlX   = Wp + 4096;
    const float* btX   = Wp + 7168;
    const float* WintY = Wp + 7200;
    const float* WlY   = Wp + 11296;
    const float* btY   = Wp + 14368;

    const size_t NB = (size_t)N * F * sizeof(float);
    const size_t EB = (size_t)E * F * sizeof(float);
    const int eg  = (E * F + 255) / 256;
    const int lg  = (LE * F + 255) / 256;
    const int nrx = (N + 31) / 32;
    const int nry = (E + 31) / 32;

    prep_k<<<16, 256, 0, stream>>>(th_mw, th_mb, th_lw, th_lb,
                                   ga_mw, ga_mb, ga_lw, ga_lb, Wp);

    hipMemsetAsync(stats, 0, 128 * sizeof(float), stream);
    hipMemsetAsync(pmpd, 0, NB, stream);
    hipMemsetAsync(zA_x, 0, NB, stream);
    hipMemsetAsync(zA_y, 0, EB, stream);

    // ---------- x side ----------
    scatter_edges_k<<<eg, 256, 0, stream>>>(y, g_dst, pmpd, E);
    main_linear_k<<<nrx, 256, 0, stream>>>(x, deg_g, pmpd, nullptr, nullptr,
                                           WintX, btX, acc_x, N);
    spmm_f32_k<<<eg, 256, 0, stream>>>(x, g_src, g_dst, zA_x, E);                  // h1
    accum_linear_k<<<nrx, 256, 0, stream>>>(zA_x, WlX, acc_x, N);
    hipMemsetAsync(zB_x, 0, NB, stream);
    spmm_f32_k<<<eg, 256, 0, stream>>>(zA_x, g_src, g_dst, zB_x, E);               // h2
    accum_linear_k<<<nrx, 256, 0, stream>>>(zB_x, WlX + 1024, acc_x, N);
    hipMemsetAsync(zA_x, 0, NB, stream);
    spmm_f32_k<<<eg, 256, 0, stream>>>(zB_x, g_src, g_dst, zA_x, E);               // h3
    hipMemsetAsync(zB_x, 0, NB, stream);
    spmm_f32_k<<<eg, 256, 0, stream>>>(zA_x, g_src, g_dst, zB_x, E);               // h4
    accum_linear_k<<<nrx, 256, 0, stream>>>(zB_x, WlX + 2048, acc_x, N);
    stats_relu_k<<<512, 256, 0, stream>>>(acc_x, N, stats);

    // ---------- y side ----------
    main_linear_k<<<nry, 256, 0, stream>>>(y, deg_lg, nullptr, x, pm_pd,
                                           WintY, btY, acc_y, E);
    spmm_f32_k<<<lg, 256, 0, stream>>>(y, lg_src, lg_dst, zA_y, LE);               // h1
    accum_linear_k<<<nry, 256, 0, stream>>>(zA_y, WlY, acc_y, E);
    hipMemsetAsync(zB_y, 0, EB, stream);
    spmm_f32_k<<<lg, 256, 0, stream>>>(zA_y, lg_src, lg_dst, zB_y, LE);            // h2
    accum_linear_k<<<nry, 256, 0, stream>>>(zB_y, WlY + 1024, acc_y, E);
    hipMemsetAsync(zA_y, 0, EB, stream);
    spmm_f32_k<<<lg, 256, 0, stream>>>(zB_y, lg_src, lg_dst, zA_y, LE);            // h3
    hipMemsetAsync(zB_y, 0, EB, stream);
    spmm_f32_k<<<lg, 256, 0, stream>>>(zA_y, lg_src, lg_dst, zB_y, LE);            // h4
    accum_linear_k<<<nry, 256, 0, stream>>>(zB_y, WlY + 2048, acc_y, E);
    stats_relu_k<<<1024, 256, 0, stream>>>(acc_y, E, stats + 64);

    // ---------- BN fold + write ----------
    scalebias_k<<<1, 64, 0, stream>>>(stats, bn_x_sc, bn_x_bi, bn_y_sc, bn_y_bi,
                                      sb, N, E);
    finalize_k<<<(N * F + 255) / 256, 256, 0, stream>>>(acc_x, sb, out, N);
    finalize_k<<<(E * F + 255) / 256, 256, 0, stream>>>(acc_y, sb + 64,
                                                        out + (size_t)N * F, E);
}

// Round 5
// 1945.362 us; speedup vs baseline: 1.2894x; 1.1434x over previous
//
#include <hip/hip_runtime.h>

#define F 32
#define BN_EPS 1e-5f
#define SCAN_CHUNK 2048  // elements scanned per block (256 thr x 8)

// All float tensors fp32 (verified R2 counters); indices int32.

// ---------------- weight prep: transpose + interleave + fuse biases ----------------
__global__ void prep_k(const float* __restrict__ th_mw, const float* __restrict__ th_mb,
                       const float* __restrict__ th_lw, const float* __restrict__ th_lb,
                       const float* __restrict__ ga_mw, const float* __restrict__ ga_mb,
                       const float* __restrict__ ga_lw, const float* __restrict__ ga_lb,
                       float* __restrict__ Wp) {
    int gs = gridDim.x * blockDim.x;
    int g0 = blockIdx.x * blockDim.x + threadIdx.x;
    float* WintX = Wp;
    float* WlX   = Wp + 4096;
    float* btX   = Wp + 7168;
    float* WintY = Wp + 7200;
    float* WlY   = Wp + 11296;
    float* btY   = Wp + 14368;
    for (int j = g0; j < 1024; j += gs) {
        int k = j >> 5, f = j & 31;
        for (int m = 0; m < 3; m++) {
            WintX[j * 4 + m] = th_mw[m * 1024 + f * 32 + k];
            WintY[j * 4 + m] = ga_mw[m * 1024 + f * 32 + k];
        }
        WintX[j * 4 + 3] = 0.f;
        WintY[j * 4 + 3] = 0.f;
    }
    for (int j = g0; j < 3072; j += gs) {
        int i = j >> 10, k = (j >> 5) & 31, f = j & 31;
        WlX[j] = th_lw[i * 1024 + f * 32 + k];
        WlY[j] = ga_lw[i * 1024 + f * 32 + k];
    }
    for (int f = g0; f < 32; f += gs) {
        float bx = 0.f, by = 0.f;
        for (int m = 0; m < 3; m++) {
            bx += th_mb[m * 32 + f] + th_lb[m * 32 + f];
            by += ga_mb[m * 32 + f] + ga_lb[m * 32 + f];
        }
        btX[f] = bx;
        btY[f] = by;
    }
}

// ---------------- CSR build ----------------
__global__ __launch_bounds__(256) void hist_k(const int* __restrict__ dst, int ne,
                                              int* __restrict__ counts) {
    int i = blockIdx.x * 256 + threadIdx.x;
    if (i < ne) atomicAdd(&counts[dst[i]], 1);
}

// per-block exclusive scan of counts -> rowptr (block-local), block totals -> bsums
__global__ __launch_bounds__(256) void scan_block_k(const int* __restrict__ counts, int n,
                                                    int* __restrict__ rowptr,
                                                    int* __restrict__ bsums) {
    __shared__ int s[256];
    int tid = threadIdx.x;
    int b0 = blockIdx.x * SCAN_CHUNK;
    int v[8], tsum = 0;
#pragma unroll
    for (int j = 0; j < 8; j++) {
        int idx = b0 + tid * 8 + j;
        v[j] = (idx < n) ? counts[idx] : 0;
        tsum += v[j];
    }
    s[tid] = tsum;
    __syncthreads();
    for (int off = 1; off < 256; off <<= 1) {
        int t = (tid >= off) ? s[tid - off] : 0;
        __syncthreads();
        s[tid] += t;
        __syncthreads();
    }
    int run = s[tid] - tsum;  // exclusive
#pragma unroll
    for (int j = 0; j < 8; j++) {
        int idx = b0 + tid * 8 + j;
        if (idx < n) rowptr[idx] = run;
        run += v[j];
    }
    if (tid == 255) bsums[blockIdx.x] = s[255];
}

// exclusive scan of block sums in place (single block, nb <= 256)
__global__ void scan_bsums_k(int* __restrict__ bsums, int nb) {
    __shared__ int s[256];
    int tid = threadIdx.x;
    int v = (tid < nb) ? bsums[tid] : 0;
    s[tid] = v;
    __syncthreads();
    for (int off = 1; off < 256; off <<= 1) {
        int t = (tid >= off) ? s[tid - off] : 0;
        __syncthreads();
        s[tid] += t;
        __syncthreads();
    }
    if (tid < nb) bsums[tid] = s[tid] - v;
}

__global__ __launch_bounds__(256) void scan_add_k(int* __restrict__ rowptr, int n, int ne,
                                                  const int* __restrict__ bsums) {
    int i = blockIdx.x * 256 + threadIdx.x;
    if (i < n) rowptr[i] += bsums[i / SCAN_CHUNK];
    if (i == 0) rowptr[n] = ne;
}

// scatter edges into CSR order; cursor starts as a copy of rowptr
__global__ __launch_bounds__(256) void scatter_g_k(const int* __restrict__ src,
                                                   const int* __restrict__ dst, int ne,
                                                   int* __restrict__ cursor,
                                                   int* __restrict__ cs, int* __restrict__ ce) {
    int i = blockIdx.x * 256 + threadIdx.x;
    if (i >= ne) return;
    int p = atomicAdd(&cursor[dst[i]], 1);
    cs[p] = src[i];
    ce[p] = i;
}

__global__ __launch_bounds__(256) void scatter_lg_k(const int* __restrict__ src,
                                                    const int* __restrict__ dst, int ne,
                                                    int* __restrict__ cursor,
                                                    int* __restrict__ cs) {
    int i = blockIdx.x * 256 + threadIdx.x;
    if (i >= ne) return;
    int p = atomicAdd(&cursor[dst[i]], 1);
    cs[p] = src[i];
}

// ---------------- pull SPMM: out[j][f] = sum_{i in row j} z[idx[i]][f] ----------------
// one 64-lane wave per destination row; lanes split into two halves handling
// alternate edges; no atomics, each output row written exactly once.
__global__ __launch_bounds__(256) void spmm_pull_k(const float* __restrict__ z,
                                                   const int* __restrict__ idx,
                                                   const int* __restrict__ rowptr,
                                                   float* __restrict__ out, int n) {
    int wave = (blockIdx.x * 256 + threadIdx.x) >> 6;
    int lane = threadIdx.x & 63;
    if (wave >= n) return;
    int f = lane & 31, half = lane >> 5;
    int b = rowptr[wave], e = rowptr[wave + 1];
    float acc = 0.f;
    for (int i = b + half; i < e; i += 2)
        acc += z[(size_t)idx[i] * F + f];
    acc += __shfl_xor(acc, 32);
    if (half == 0) out[(size_t)wave * F + f] = acc;
}

// ---------------- main linear, 32 rows/block, transposed LDS tiles ----------------
__global__ __launch_bounds__(256) void main_linear_k(
    const float* __restrict__ in0, const float* __restrict__ deg,
    const float* __restrict__ aux32, const float* __restrict__ auxsrc,
    const int* __restrict__ auxidx,
    const float* __restrict__ Wint_g, const float* __restrict__ bt,
    float* __restrict__ acc, int R)
{
    __shared__ float Wint[4096];
    __shared__ float srow_t[32 * 36];
    __shared__ float arow_t[32 * 36];
    __shared__ float sdeg[32];

    int tid = threadIdx.x;
    {
        const float4* g4 = (const float4*)Wint_g;
        float4* s4 = (float4*)Wint;
#pragma unroll
        for (int i = 0; i < 4; i++) s4[tid + i * 256] = g4[tid + i * 256];
    }
    int base = blockIdx.x * 32;
    int r = tid >> 3;
    int c = (tid & 7) * 4;
    int row = base + r;
    float4 sv = make_float4(0.f, 0.f, 0.f, 0.f);
    float4 av = make_float4(0.f, 0.f, 0.f, 0.f);
    if (row < R) {
        sv = *(const float4*)(in0 + (size_t)row * F + c);
        if (aux32) av = *(const float4*)(aux32 + (size_t)row * F + c);
        else       av = *(const float4*)(auxsrc + (size_t)auxidx[row] * F + c);
    }
    srow_t[(c + 0) * 36 + r] = sv.x;
    srow_t[(c + 1) * 36 + r] = sv.y;
    srow_t[(c + 2) * 36 + r] = sv.z;
    srow_t[(c + 3) * 36 + r] = sv.w;
    arow_t[(c + 0) * 36 + r] = av.x;
    arow_t[(c + 1) * 36 + r] = av.y;
    arow_t[(c + 2) * 36 + r] = av.z;
    arow_t[(c + 3) * 36 + r] = av.w;
    if (tid < 32) sdeg[tid] = (base + tid < R) ? deg[base + tid] : 0.f;
    __syncthreads();

    int f = tid & 31, lr = tid >> 5;
    int r0 = lr * 4;
    float a0[4] = {0.f, 0.f, 0.f, 0.f};
    float a1[4] = {0.f, 0.f, 0.f, 0.f};
    float a2[4] = {0.f, 0.f, 0.f, 0.f};
    const float4* W4 = (const float4*)Wint;
#pragma unroll
    for (int k = 0; k < 32; k++) {
        float4 w = W4[k * 32 + f];
        float4 s = *(const float4*)(srow_t + k * 36 + r0);
        float4 a = *(const float4*)(arow_t + k * 36 + r0);
        a0[0] = fmaf(s.x, w.x, a0[0]); a1[0] = fmaf(s.x, w.y, a1[0]); a2[0] = fmaf(a.x, w.z, a2[0]);
        a0[1] = fmaf(s.y, w.x, a0[1]); a1[1] = fmaf(s.y, w.y, a1[1]); a2[1] = fmaf(a.y, w.z, a2[1]);
        a0[2] = fmaf(s.z, w.x, a0[2]); a1[2] = fmaf(s.z, w.y, a1[2]); a2[2] = fmaf(a.z, w.z, a2[2]);
        a0[3] = fmaf(s.w, w.x, a0[3]); a1[3] = fmaf(s.w, w.y, a1[3]); a2[3] = fmaf(a.w, w.z, a2[3]);
    }
    float btf = bt[f];
#pragma unroll
    for (int j = 0; j < 4; j++) {
        int rr = base + r0 + j;
        if (rr < R) acc[(size_t)rr * F + f] = a0[j] + sdeg[r0 + j] * a1[j] + a2[j] + btf;
    }
}

// ---------------- acc += z @ W^T, 32 rows/block ----------------
__global__ __launch_bounds__(256) void accum_linear_k(const float* __restrict__ z,
                                                      const float* __restrict__ Wl,
                                                      float* __restrict__ acc, int R) {
    __shared__ float Wt[1024];
    __shared__ float zt[32 * 36];
    int tid = threadIdx.x;
    ((float4*)Wt)[tid] = ((const float4*)Wl)[tid];
    int base = blockIdx.x * 32;
    int r = tid >> 3;
    int c = (tid & 7) * 4;
    int row = base + r;
    float4 v = make_float4(0.f, 0.f, 0.f, 0.f);
    if (row < R) v = *(const float4*)(z + (size_t)row * F + c);
    zt[(c + 0) * 36 + r] = v.x;
    zt[(c + 1) * 36 + r] = v.y;
    zt[(c + 2) * 36 + r] = v.z;
    zt[(c + 3) * 36 + r] = v.w;
    __syncthreads();

    int f = tid & 31, lr = tid >> 5;
    int r0 = lr * 4;
    float a[4] = {0.f, 0.f, 0.f, 0.f};
#pragma unroll
    for (int k = 0; k < 32; k++) {
        float w = Wt[k * 32 + f];
        float4 s = *(const float4*)(zt + k * 36 + r0);
        a[0] = fmaf(s.x, w, a[0]);
        a[1] = fmaf(s.y, w, a[1]);
        a[2] = fmaf(s.z, w, a[2]);
        a[3] = fmaf(s.w, w, a[3]);
    }
#pragma unroll
    for (int j = 0; j < 4; j++) {
        int rr = base + r0 + j;
        if (rr < R) acc[(size_t)rr * F + f] += a[j];
    }
}

// ---------------- in-place half-ReLU + per-column sum/sumsq ----------------
__global__ __launch_bounds__(256) void stats_relu_k(float* __restrict__ acc, int R,
                                                    float* __restrict__ stats) {
    int total = R * F;
    int stride = gridDim.x * 256;
    float s = 0.f, ss = 0.f;
    for (int i = blockIdx.x * 256 + threadIdx.x; i < total; i += stride) {
        float v = acc[i];
        if ((i & 31) >= 16) v = fmaxf(v, 0.f);
        acc[i] = v;
        s += v;
        ss += v * v;
    }
    __shared__ float Ss[256], Sq[256];
    Ss[threadIdx.x] = s; Sq[threadIdx.x] = ss;
    __syncthreads();
    for (int off = 128; off >= 32; off >>= 1) {
        if (threadIdx.x < off) {
            Ss[threadIdx.x] += Ss[threadIdx.x + off];
            Sq[threadIdx.x] += Sq[threadIdx.x + off];
        }
        __syncthreads();
    }
    if (threadIdx.x < 32) {
        atomicAdd(&stats[threadIdx.x], Ss[threadIdx.x]);
        atomicAdd(&stats[32 + threadIdx.x], Sq[threadIdx.x]);
    }
}

__global__ void scalebias_k(const float* __restrict__ stats,
                            const float* __restrict__ sc_x, const float* __restrict__ bi_x,
                            const float* __restrict__ sc_y, const float* __restrict__ bi_y,
                            float* __restrict__ sb, int Rx, int Ry) {
    int tid = threadIdx.x;
    if (tid >= 64) return;
    int side = tid >> 5, f = tid & 31;
    const float* st = stats + side * 64;
    float Rn = side ? (float)Ry : (float)Rx;
    float mean = st[f] / Rn;
    float var = st[32 + f] / Rn - mean * mean;
    float a = rsqrtf(var + BN_EPS) * (side ? sc_y[f] : sc_x[f]);
    float b = (side ? bi_y[f] : bi_x[f]) - mean * a;
    sb[side * 64 + f] = a;
    sb[side * 64 + 32 + f] = b;
}

__global__ __launch_bounds__(256) void finalize_k(const float* __restrict__ acc,
                                                  const float* __restrict__ sb,
                                                  float* __restrict__ out, int R) {
    int i = blockIdx.x * 256 + threadIdx.x;
    if (i >= R * F) return;
    int f = i & 31;
    out[i] = acc[i] * sb[f] + sb[32 + f];
}

extern "C" void kernel_launch(void* const* d_in, const int* in_sizes, int n_in,
                              void* d_out, int out_size, void* d_ws, size_t ws_size,
                              hipStream_t stream) {
    const float* x       = (const float*)d_in[0];
    const float* y       = (const float*)d_in[1];
    const float* deg_g   = (const float*)d_in[2];
    const float* deg_lg  = (const float*)d_in[3];
    const float* th_mw   = (const float*)d_in[4];
    const float* th_mb   = (const float*)d_in[5];
    const float* th_lw   = (const float*)d_in[6];
    const float* th_lb   = (const float*)d_in[7];
    const float* ga_mw   = (const float*)d_in[8];
    const float* ga_mb   = (const float*)d_in[9];
    const float* ga_lw   = (const float*)d_in[10];
    const float* ga_lb   = (const float*)d_in[11];
    const float* bn_x_sc = (const float*)d_in[12];
    const float* bn_x_bi = (const float*)d_in[13];
    const float* bn_y_sc = (const float*)d_in[14];
    const float* bn_y_bi = (const float*)d_in[15];
    const int*   g_src   = (const int*)d_in[16];
    const int*   g_dst   = (const int*)d_in[17];
    const int*   lg_src  = (const int*)d_in[18];
    const int*   lg_dst  = (const int*)d_in[19];
    const int*   pm_pd   = (const int*)d_in[20];
    float* out = (float*)d_out;

    const int N  = in_sizes[0] / F;
    const int E  = in_sizes[1] / F;
    const int LE = in_sizes[18];

    // ---- workspace layout ----
    float* ws    = (float*)d_ws;
    float* stats = ws;                 // 128
    float* sb    = ws + 128;           // 128
    float* Wp    = ws + 256;           // 14400
    float* zA_x  = ws + 256 + 14400;
    float* zB_x  = zA_x + (size_t)N * F;
    float* acc_x = zB_x + (size_t)N * F;
    float* pmpd  = acc_x + (size_t)N * F;
    float* zA_y  = pmpd + (size_t)N * F;
    float* zB_y  = zA_y + (size_t)E * F;
    float* acc_y = zB_y + (size_t)E * F;
    int* ip        = (int*)(acc_y + (size_t)E * F);
    int* rowptr_g  = ip;                    // N+1
    int* counts_g  = rowptr_g + (N + 1);    // N (doubles as scatter cursor)
    int* cs_g      = counts_g + N;          // E (src sorted by dst)
    int* ce_g      = cs_g + E;              // E (edge id sorted by dst)
    int* rowptr_lg = ce_g + E;              // E+1
    int* counts_lg = rowptr_lg + (E + 1);   // E
    int* cs_lg     = counts_lg + E;         // LE
    int* bsums_g   = cs_lg + LE;            // 256
    int* bsums_lg  = bsums_g + 256;         // 256

    const float* WintX = Wp;
    const float* WlX   = Wp + 4096;
    const float* btX   = Wp + 7168;
    const float* WintY = Wp + 7200;
    const float* WlY   = Wp + 11296;
    const float* btY   = Wp + 14368;

    const int nrx = (N + 31) / 32;
    const int nry = (E + 31) / 32;
    const int pull_gx = (N + 3) / 4;   // 4 waves/block, 1 row/wave
    const int pull_gy = (E + 3) / 4;
    const int nbs_g  = (N + SCAN_CHUNK - 1) / SCAN_CHUNK;
    const int nbs_lg = (E + SCAN_CHUNK - 1) / SCAN_CHUNK;

    prep_k<<<16, 256, 0, stream>>>(th_mw, th_mb, th_lw, th_lb,
                                   ga_mw, ga_mb, ga_lw, ga_lb, Wp);
    hipMemsetAsync(stats, 0, 128 * sizeof(float), stream);
    hipMemsetAsync(counts_g, 0, (size_t)N * sizeof(int), stream);
    hipMemsetAsync(counts_lg, 0, (size_t)E * sizeof(int), stream);

    // ---- CSR build: g ----
    hist_k<<<(E + 255) / 256, 256, 0, stream>>>(g_dst, E, counts_g);
    scan_block_k<<<nbs_g, 256, 0, stream>>>(counts_g, N, rowptr_g, bsums_g);
    scan_bsums_k<<<1, 256, 0, stream>>>(bsums_g, nbs_g);
    scan_add_k<<<(N + 255) / 256, 256, 0, stream>>>(rowptr_g, N, E, bsums_g);
    hipMemcpyAsync(counts_g, rowptr_g, (size_t)N * sizeof(int),
                   hipMemcpyDeviceToDevice, stream);
    scatter_g_k<<<(E + 255) / 256, 256, 0, stream>>>(g_src, g_dst, E,
                                                     counts_g, cs_g, ce_g);
    // ---- CSR build: lg ----
    hist_k<<<(LE + 255) / 256, 256, 0, stream>>>(lg_dst, LE, counts_lg);
    scan_block_k<<<nbs_lg, 256, 0, stream>>>(counts_lg, E, rowptr_lg, bsums_lg);
    scan_bsums_k<<<1, 256, 0, stream>>>(bsums_lg, nbs_lg);
    scan_add_k<<<(E + 255) / 256, 256, 0, stream>>>(rowptr_lg, E, LE, bsums_lg);
    hipMemcpyAsync(counts_lg, rowptr_lg, (size_t)E * sizeof(int),
                   hipMemcpyDeviceToDevice, stream);
    scatter_lg_k<<<(LE + 255) / 256, 256, 0, stream>>>(lg_src, lg_dst, LE,
                                                       counts_lg, cs_lg);

    // ---------- x side ----------
    spmm_pull_k<<<pull_gx, 256, 0, stream>>>(y, ce_g, rowptr_g, pmpd, N);      // pmpd_y
    main_linear_k<<<nrx, 256, 0, stream>>>(x, deg_g, pmpd, nullptr, nullptr,
                                           WintX, btX, acc_x, N);
    spmm_pull_k<<<pull_gx, 256, 0, stream>>>(x, cs_g, rowptr_g, zA_x, N);      // h1
    accum_linear_k<<<nrx, 256, 0, stream>>>(zA_x, WlX, acc_x, N);
    spmm_pull_k<<<pull_gx, 256, 0, stream>>>(zA_x, cs_g, rowptr_g, zB_x, N);   // h2
    accum_linear_k<<<nrx, 256, 0, stream>>>(zB_x, WlX + 1024, acc_x, N);
    spmm_pull_k<<<pull_gx, 256, 0, stream>>>(zB_x, cs_g, rowptr_g, zA_x, N);   // h3
    spmm_pull_k<<<pull_gx, 256, 0, stream>>>(zA_x, cs_g, rowptr_g, zB_x, N);   // h4
    accum_linear_k<<<nrx, 256, 0, stream>>>(zB_x, WlX + 2048, acc_x, N);
    stats_relu_k<<<512, 256, 0, stream>>>(acc_x, N, stats);

    // ---------- y side ----------
    main_linear_k<<<nry, 256, 0, stream>>>(y, deg_lg, nullptr, x, pm_pd,
                                           WintY, btY, acc_y, E);
    spmm_pull_k<<<pull_gy, 256, 0, stream>>>(y, cs_lg, rowptr_lg, zA_y, E);    // h1
    accum_linear_k<<<nry, 256, 0, stream>>>(zA_y, WlY, acc_y, E);
    spmm_pull_k<<<pull_gy, 256, 0, stream>>>(zA_y, cs_lg, rowptr_lg, zB_y, E); // h2
    accum_linear_k<<<nry, 256, 0, stream>>>(zB_y, WlY + 1024, acc_y, E);
    spmm_pull_k<<<pull_gy, 256, 0, stream>>>(zB_y, cs_lg, rowptr_lg, zA_y, E); // h3
    spmm_pull_k<<<pull_gy, 256, 0, stream>>>(zA_y, cs_lg, rowptr_lg, zB_y, E); // h4
    accum_linear_k<<<nry, 256, 0, stream>>>(zB_y, WlY + 2048, acc_y, E);
    stats_relu_k<<<1024, 256, 0, stream>>>(acc_y, E, stats + 64);

    // ---------- BN fold + write ----------
    scalebias_k<<<1, 64, 0, stream>>>(stats, bn_x_sc, bn_x_bi, bn_y_sc, bn_y_bi,
                                      sb, N, E);
    finalize_k<<<(N * F + 255) / 256, 256, 0, stream>>>(acc_x, sb, out, N);
    finalize_k<<<(E * F + 255) / 256, 256, 0, stream>>>(acc_y, sb + 64,
                                                        out + (size_t)N * F, E);
}

// Round 6
// 1344.973 us; speedup vs baseline: 1.8650x; 1.4464x over previous
//
#include <hip/hip_runtime.h>

#define F 32
#define BN_EPS 1e-5f
#define SCAN_CHUNK 2048
#define BSH 11
#define BDST (1 << BSH)   // dsts per bucket
#define TILEE 8192        // edges per partition block

// All float tensors fp32 (verified R2 counters); indices int32.

// ---------------- weight prep ----------------
__global__ void prep_k(const float* __restrict__ th_mw, const float* __restrict__ th_mb,
                       const float* __restrict__ th_lw, const float* __restrict__ th_lb,
                       const float* __restrict__ ga_mw, const float* __restrict__ ga_mb,
                       const float* __restrict__ ga_lw, const float* __restrict__ ga_lb,
                       float* __restrict__ Wp) {
    int gs = gridDim.x * blockDim.x;
    int g0 = blockIdx.x * blockDim.x + threadIdx.x;
    float* WintX = Wp;
    float* WlX   = Wp + 4096;
    float* btX   = Wp + 7168;
    float* WintY = Wp + 7200;
    float* WlY   = Wp + 11296;
    float* btY   = Wp + 14368;
    for (int j = g0; j < 1024; j += gs) {
        int k = j >> 5, f = j & 31;
        for (int m = 0; m < 3; m++) {
            WintX[j * 4 + m] = th_mw[m * 1024 + f * 32 + k];
            WintY[j * 4 + m] = ga_mw[m * 1024 + f * 32 + k];
        }
        WintX[j * 4 + 3] = 0.f;
        WintY[j * 4 + 3] = 0.f;
    }
    for (int j = g0; j < 3072; j += gs) {
        int i = j >> 10, k = (j >> 5) & 31, f = j & 31;
        WlX[j] = th_lw[i * 1024 + f * 32 + k];
        WlY[j] = ga_lw[i * 1024 + f * 32 + k];
    }
    for (int f = g0; f < 32; f += gs) {
        float bx = 0.f, by = 0.f;
        for (int m = 0; m < 3; m++) {
            bx += th_mb[m * 32 + f] + th_lb[m * 32 + f];
            by += ga_mb[m * 32 + f] + ga_lb[m * 32 + f];
        }
        btX[f] = bx;
        btY[f] = by;
    }
}

// ---------------- g-graph CSR build (small, keep atomic path) ----------------
__global__ __launch_bounds__(256) void hist_k(const int* __restrict__ dst, int ne,
                                              int* __restrict__ counts) {
    int i = blockIdx.x * 256 + threadIdx.x;
    if (i < ne) atomicAdd(&counts[dst[i]], 1);
}

__global__ __launch_bounds__(256) void scan_block_k(const int* __restrict__ counts, int n,
                                                    int* __restrict__ rowptr,
                                                    int* __restrict__ bsums) {
    __shared__ int s[256];
    int tid = threadIdx.x;
    int b0 = blockIdx.x * SCAN_CHUNK;
    int v[8], tsum = 0;
#pragma unroll
    for (int j = 0; j < 8; j++) {
        int idx = b0 + tid * 8 + j;
        v[j] = (idx < n) ? counts[idx] : 0;
        tsum += v[j];
    }
    s[tid] = tsum;
    __syncthreads();
    for (int off = 1; off < 256; off <<= 1) {
        int t = (tid >= off) ? s[tid - off] : 0;
        __syncthreads();
        s[tid] += t;
        __syncthreads();
    }
    int run = s[tid] - tsum;
#pragma unroll
    for (int j = 0; j < 8; j++) {
        int idx = b0 + tid * 8 + j;
        if (idx < n) rowptr[idx] = run;
        run += v[j];
    }
    if (tid == 255) bsums[blockIdx.x] = s[255];
}

__global__ void scan_bsums_k(int* __restrict__ bsums, int nb) {
    __shared__ int s[256];
    int tid = threadIdx.x;
    int v = (tid < nb) ? bsums[tid] : 0;
    s[tid] = v;
    __syncthreads();
    for (int off = 1; off < 256; off <<= 1) {
        int t = (tid >= off) ? s[tid - off] : 0;
        __syncthreads();
        s[tid] += t;
        __syncthreads();
    }
    if (tid < nb) bsums[tid] = s[tid] - v;
}

__global__ __launch_bounds__(256) void scan_add_k(int* __restrict__ rowptr, int n, int ne,
                                                  const int* __restrict__ bsums) {
    int i = blockIdx.x * 256 + threadIdx.x;
    if (i < n) rowptr[i] += bsums[i / SCAN_CHUNK];
    if (i == 0) rowptr[n] = ne;
}

__global__ __launch_bounds__(256) void scatter_g_k(const int* __restrict__ src,
                                                   const int* __restrict__ dst, int ne,
                                                   int* __restrict__ cursor,
                                                   int* __restrict__ cs, int* __restrict__ ce) {
    int i = blockIdx.x * 256 + threadIdx.x;
    if (i >= ne) return;
    int p = atomicAdd(&cursor[dst[i]], 1);
    cs[p] = src[i];
    ce[p] = i;
}

// ---------------- lg CSR build: partitioned, write-amplification-free ----------------
__global__ __launch_bounds__(256) void bucket_hist_k(const int* __restrict__ dst, int ne,
                                                     int* __restrict__ bcnt, int nbuk) {
    __shared__ int h[1024];
    for (int i = threadIdx.x; i < nbuk; i += 256) h[i] = 0;
    __syncthreads();
    for (int i = blockIdx.x * 256 + threadIdx.x; i < ne; i += gridDim.x * 256)
        atomicAdd(&h[dst[i] >> BSH], 1);
    __syncthreads();
    for (int i = threadIdx.x; i < nbuk; i += 256)
        if (h[i]) atomicAdd(&bcnt[i], h[i]);
}

// single block: exclusive scan of bcnt -> bstart (+cursorA copy); nbuk <= 1024
__global__ void bucket_scan_k(const int* __restrict__ bcnt, int nbuk, int ne,
                              int* __restrict__ bstart, int* __restrict__ cursorA) {
    __shared__ int psum[256];
    int tid = threadIdx.x;
    int v[4], s = 0;
#pragma unroll
    for (int j = 0; j < 4; j++) {
        int idx = tid * 4 + j;
        v[j] = (idx < nbuk) ? bcnt[idx] : 0;
        s += v[j];
    }
    psum[tid] = s;
    __syncthreads();
    for (int o = 1; o < 256; o <<= 1) {
        int t = (tid >= o) ? psum[tid - o] : 0;
        __syncthreads();
        psum[tid] += t;
        __syncthreads();
    }
    int run = psum[tid] - s;
#pragma unroll
    for (int j = 0; j < 4; j++) {
        int idx = tid * 4 + j;
        if (idx < nbuk) { bstart[idx] = run; cursorA[idx] = run; }
        run += v[j];
    }
    if (tid == 0) bstart[nbuk] = ne;
}

// phase A: per-tile LDS histogram -> block-reserve runs -> contiguous-ish int2 writes
__global__ __launch_bounds__(256) void partA_k(const int* __restrict__ src,
                                               const int* __restrict__ dst, int ne,
                                               int* __restrict__ cursorA,
                                               int2* __restrict__ buf, int nbuk) {
    __shared__ int h[1024];
    __shared__ int base[1024];
    int t0 = blockIdx.x * TILEE;
    int tend = t0 + TILEE < ne ? t0 + TILEE : ne;
    for (int i = threadIdx.x; i < nbuk; i += 256) h[i] = 0;
    __syncthreads();
    for (int i = t0 + threadIdx.x; i < tend; i += 256)
        atomicAdd(&h[dst[i] >> BSH], 1);
    __syncthreads();
    for (int i = threadIdx.x; i < nbuk; i += 256) {
        int c = h[i];
        base[i] = c ? atomicAdd(&cursorA[i], c) : 0;
        h[i] = 0;  // reuse as block-local cursor
    }
    __syncthreads();
    for (int i = t0 + threadIdx.x; i < tend; i += 256) {
        int d = dst[i];
        int bkt = d >> BSH;
        int pos = base[bkt] + atomicAdd(&h[bkt], 1);
        buf[pos] = make_int2(src[i], d & (BDST - 1));
    }
}

// phase B: one block per bucket; per-dst count+scan in LDS, write cs into the
// bucket's private contiguous region; also emits rowptr for this bucket.
__global__ __launch_bounds__(256) void partB_k(const int2* __restrict__ buf,
                                               const int* __restrict__ bstart,
                                               int ndst, int ne,
                                               int* __restrict__ cs,
                                               int* __restrict__ rowptr) {
    __shared__ int off[BDST];
    __shared__ int cur[BDST];
    __shared__ int psum[256];
    int b = blockIdx.x;
    int tid = threadIdx.x;
    int lo = bstart[b], hi = bstart[b + 1];
    for (int d = tid; d < BDST; d += 256) { off[d] = 0; cur[d] = 0; }
    __syncthreads();
    for (int i = lo + tid; i < hi; i += 256)
        atomicAdd(&off[buf[i].y], 1);
    __syncthreads();
    int base_d = tid * 8;
    int loc[8], s = 0;
#pragma unroll
    for (int j = 0; j < 8; j++) { loc[j] = off[base_d + j]; s += loc[j]; }
    psum[tid] = s;
    __syncthreads();
    for (int o = 1; o < 256; o <<= 1) {
        int t = (tid >= o) ? psum[tid - o] : 0;
        __syncthreads();
        psum[tid] += t;
        __syncthreads();
    }
    int run = psum[tid] - s;
#pragma unroll
    for (int j = 0; j < 8; j++) { int c = loc[j]; off[base_d + j] = run; run += c; }
    __syncthreads();
    int dbase = b << BSH;
    for (int d = tid; d < BDST; d += 256) {
        int gd = dbase + d;
        if (gd < ndst) rowptr[gd] = lo + off[d];
    }
    if (b == 0 && tid == 0) rowptr[ndst] = ne;
    for (int i = lo + tid; i < hi; i += 256) {
        int2 p = buf[i];
        int pos = lo + off[p.y] + atomicAdd(&cur[p.y], 1);
        cs[pos] = p.x;
    }
}

// ---------------- pull SPMM, float4 / 8-edge-parallel ----------------
// one wave per dst row: edge slot = lane>>3 (8 parallel edges => 8 lines/instr),
// feature quad = (lane&7)*4; butterfly-reduce over edge slots.
__global__ __launch_bounds__(256) void spmm_pull_k(const float* __restrict__ z,
                                                   const int* __restrict__ idx,
                                                   const int* __restrict__ rowptr,
                                                   float* __restrict__ out, int n) {
    int wave = (blockIdx.x * 256 + threadIdx.x) >> 6;
    if (wave >= n) return;
    int lane = threadIdx.x & 63;
    int fg = (lane & 7) * 4;
    int es = lane >> 3;
    int b = rowptr[wave], e = rowptr[wave + 1];
    float4 acc = make_float4(0.f, 0.f, 0.f, 0.f);
    for (int i = b + es; i < e; i += 8) {
        float4 v = *(const float4*)(z + (size_t)idx[i] * F + fg);
        acc.x += v.x; acc.y += v.y; acc.z += v.z; acc.w += v.w;
    }
#pragma unroll
    for (int s = 8; s < 64; s <<= 1) {
        acc.x += __shfl_xor(acc.x, s);
        acc.y += __shfl_xor(acc.y, s);
        acc.z += __shfl_xor(acc.z, s);
        acc.w += __shfl_xor(acc.w, s);
    }
    if (es == 0) *(float4*)(out + (size_t)wave * F + fg) = acc;
}

// ---------------- main linear, 32 rows/block ----------------
__global__ __launch_bounds__(256) void main_linear_k(
    const float* __restrict__ in0, const float* __restrict__ deg,
    const float* __restrict__ aux32, const float* __restrict__ auxsrc,
    const int* __restrict__ auxidx,
    const float* __restrict__ Wint_g, const float* __restrict__ bt,
    float* __restrict__ acc, int R)
{
    __shared__ float Wint[4096];
    __shared__ float srow_t[32 * 36];
    __shared__ float arow_t[32 * 36];
    __shared__ float sdeg[32];

    int tid = threadIdx.x;
    {
        const float4* g4 = (const float4*)Wint_g;
        float4* s4 = (float4*)Wint;
#pragma unroll
        for (int i = 0; i < 4; i++) s4[tid + i * 256] = g4[tid + i * 256];
    }
    int base = blockIdx.x * 32;
    int r = tid >> 3;
    int c = (tid & 7) * 4;
    int row = base + r;
    float4 sv = make_float4(0.f, 0.f, 0.f, 0.f);
    float4 av = make_float4(0.f, 0.f, 0.f, 0.f);
    if (row < R) {
        sv = *(const float4*)(in0 + (size_t)row * F + c);
        if (aux32) av = *(const float4*)(aux32 + (size_t)row * F + c);
        else       av = *(const float4*)(auxsrc + (size_t)auxidx[row] * F + c);
    }
    srow_t[(c + 0) * 36 + r] = sv.x;
    srow_t[(c + 1) * 36 + r] = sv.y;
    srow_t[(c + 2) * 36 + r] = sv.z;
    srow_t[(c + 3) * 36 + r] = sv.w;
    arow_t[(c + 0) * 36 + r] = av.x;
    arow_t[(c + 1) * 36 + r] = av.y;
    arow_t[(c + 2) * 36 + r] = av.z;
    arow_t[(c + 3) * 36 + r] = av.w;
    if (tid < 32) sdeg[tid] = (base + tid < R) ? deg[base + tid] : 0.f;
    __syncthreads();

    int f = tid & 31, lr = tid >> 5;
    int r0 = lr * 4;
    float a0[4] = {0.f, 0.f, 0.f, 0.f};
    float a1[4] = {0.f, 0.f, 0.f, 0.f};
    float a2[4] = {0.f, 0.f, 0.f, 0.f};
    const float4* W4 = (const float4*)Wint;
#pragma unroll
    for (int k = 0; k < 32; k++) {
        float4 w = W4[k * 32 + f];
        float4 s = *(const float4*)(srow_t + k * 36 + r0);
        float4 a = *(const float4*)(arow_t + k * 36 + r0);
        a0[0] = fmaf(s.x, w.x, a0[0]); a1[0] = fmaf(s.x, w.y, a1[0]); a2[0] = fmaf(a.x, w.z, a2[0]);
        a0[1] = fmaf(s.y, w.x, a0[1]); a1[1] = fmaf(s.y, w.y, a1[1]); a2[1] = fmaf(a.y, w.z, a2[1]);
        a0[2] = fmaf(s.z, w.x, a0[2]); a1[2] = fmaf(s.z, w.y, a1[2]); a2[2] = fmaf(a.z, w.z, a2[2]);
        a0[3] = fmaf(s.w, w.x, a0[3]); a1[3] = fmaf(s.w, w.y, a1[3]); a2[3] = fmaf(a.w, w.z, a2[3]);
    }
    float btf = bt[f];
#pragma unroll
    for (int j = 0; j < 4; j++) {
        int rr = base + r0 + j;
        if (rr < R) acc[(size_t)rr * F + f] = a0[j] + sdeg[r0 + j] * a1[j] + a2[j] + btf;
    }
}

// ---------------- acc += z @ W^T ----------------
__global__ __launch_bounds__(256) void accum_linear_k(const float* __restrict__ z,
                                                      const float* __restrict__ Wl,
                                                      float* __restrict__ acc, int R) {
    __shared__ float Wt[1024];
    __shared__ float zt[32 * 36];
    int tid = threadIdx.x;
    ((float4*)Wt)[tid] = ((const float4*)Wl)[tid];
    int base = blockIdx.x * 32;
    int r = tid >> 3;
    int c = (tid & 7) * 4;
    int row = base + r;
    float4 v = make_float4(0.f, 0.f, 0.f, 0.f);
    if (row < R) v = *(const float4*)(z + (size_t)row * F + c);
    zt[(c + 0) * 36 + r] = v.x;
    zt[(c + 1) * 36 + r] = v.y;
    zt[(c + 2) * 36 + r] = v.z;
    zt[(c + 3) * 36 + r] = v.w;
    __syncthreads();

    int f = tid & 31, lr = tid >> 5;
    int r0 = lr * 4;
    float a[4] = {0.f, 0.f, 0.f, 0.f};
#pragma unroll
    for (int k = 0; k < 32; k++) {
        float w = Wt[k * 32 + f];
        float4 s = *(const float4*)(zt + k * 36 + r0);
        a[0] = fmaf(s.x, w, a[0]);
        a[1] = fmaf(s.y, w, a[1]);
        a[2] = fmaf(s.z, w, a[2]);
        a[3] = fmaf(s.w, w, a[3]);
    }
#pragma unroll
    for (int j = 0; j < 4; j++) {
        int rr = base + r0 + j;
        if (rr < R) acc[(size_t)rr * F + f] += a[j];
    }
}

// ---------------- half-ReLU + per-column stats ----------------
__global__ __launch_bounds__(256) void stats_relu_k(float* __restrict__ acc, int R,
                                                    float* __restrict__ stats) {
    int total = R * F;
    int stride = gridDim.x * 256;
    float s = 0.f, ss = 0.f;
    for (int i = blockIdx.x * 256 + threadIdx.x; i < total; i += stride) {
        float v = acc[i];
        if ((i & 31) >= 16) v = fmaxf(v, 0.f);
        acc[i] = v;
        s += v;
        ss += v * v;
    }
    __shared__ float Ss[256], Sq[256];
    Ss[threadIdx.x] = s; Sq[threadIdx.x] = ss;
    __syncthreads();
    for (int off = 128; off >= 32; off >>= 1) {
        if (threadIdx.x < off) {
            Ss[threadIdx.x] += Ss[threadIdx.x + off];
            Sq[threadIdx.x] += Sq[threadIdx.x + off];
        }
        __syncthreads();
    }
    if (threadIdx.x < 32) {
        atomicAdd(&stats[threadIdx.x], Ss[threadIdx.x]);
        atomicAdd(&stats[32 + threadIdx.x], Sq[threadIdx.x]);
    }
}

__global__ void scalebias_k(const float* __restrict__ stats,
                            const float* __restrict__ sc_x, const float* __restrict__ bi_x,
                            const float* __restrict__ sc_y, const float* __restrict__ bi_y,
                            float* __restrict__ sb, int Rx, int Ry) {
    int tid = threadIdx.x;
    if (tid >= 64) return;
    int side = tid >> 5, f = tid & 31;
    const float* st = stats + side * 64;
    float Rn = side ? (float)Ry : (float)Rx;
    float mean = st[f] / Rn;
    float var = st[32 + f] / Rn - mean * mean;
    float a = rsqrtf(var + BN_EPS) * (side ? sc_y[f] : sc_x[f]);
    float b = (side ? bi_y[f] : bi_x[f]) - mean * a;
    sb[side * 64 + f] = a;
    sb[side * 64 + 32 + f] = b;
}

__global__ __launch_bounds__(256) void finalize_k(const float* __restrict__ acc,
                                                  const float* __restrict__ sb,
                                                  float* __restrict__ out, int R) {
    int i = blockIdx.x * 256 + threadIdx.x;
    if (i >= R * F) return;
    int f = i & 31;
    out[i] = acc[i] * sb[f] + sb[32 + f];
}

extern "C" void kernel_launch(void* const* d_in, const int* in_sizes, int n_in,
                              void* d_out, int out_size, void* d_ws, size_t ws_size,
                              hipStream_t stream) {
    const float* x       = (const float*)d_in[0];
    const float* y       = (const float*)d_in[1];
    const float* deg_g   = (const float*)d_in[2];
    const float* deg_lg  = (const float*)d_in[3];
    const float* th_mw   = (const float*)d_in[4];
    const float* th_mb   = (const float*)d_in[5];
    const float* th_lw   = (const float*)d_in[6];
    const float* th_lb   = (const float*)d_in[7];
    const float* ga_mw   = (const float*)d_in[8];
    const float* ga_mb   = (const float*)d_in[9];
    const float* ga_lw   = (const float*)d_in[10];
    const float* ga_lb   = (const float*)d_in[11];
    const float* bn_x_sc = (const float*)d_in[12];
    const float* bn_x_bi = (const float*)d_in[13];
    const float* bn_y_sc = (const float*)d_in[14];
    const float* bn_y_bi = (const float*)d_in[15];
    const int*   g_src   = (const int*)d_in[16];
    const int*   g_dst   = (const int*)d_in[17];
    const int*   lg_src  = (const int*)d_in[18];
    const int*   lg_dst  = (const int*)d_in[19];
    const int*   pm_pd   = (const int*)d_in[20];
    float* out = (float*)d_out;

    const int N  = in_sizes[0] / F;
    const int E  = in_sizes[1] / F;
    const int LE = in_sizes[18];
    const int nbuk = (E + BDST - 1) >> BSH;

    // ---- workspace ----
    float* ws    = (float*)d_ws;
    float* stats = ws;                 // 128
    float* sb    = ws + 128;           // 128
    float* Wp    = ws + 256;           // 14400
    float* zA_x  = ws + 256 + 14400;
    float* zB_x  = zA_x + (size_t)N * F;
    float* acc_x = zB_x + (size_t)N * F;
    float* pmpd  = acc_x + (size_t)N * F;
    float* zA_y  = pmpd + (size_t)N * F;
    float* zB_y  = zA_y + (size_t)E * F;
    float* acc_y = zB_y + (size_t)E * F;
    int* ip        = (int*)(acc_y + (size_t)E * F);
    int* rowptr_g  = ip;                    // N+1
    int* counts_g  = rowptr_g + (N + 1);    // N
    int* cs_g      = counts_g + N;          // E
    int* ce_g      = cs_g + E;              // E
    int* rowptr_lg = ce_g + E;              // E+1
    int* cs_lg     = rowptr_lg + (E + 1);   // LE
    int* bcnt      = cs_lg + LE;            // 1024
    int* bstart    = bcnt + 1024;           // 1025
    int* cursorA   = bstart + 1025;         // 1024
    int* bsums_g   = cursorA + 1024;        // 256
    int2* buf      = (int2*)zB_y;           // LE int2 (aliased; free until h2-y pull)

    const float* WintX = Wp;
    const float* WlX   = Wp + 4096;
    const float* btX   = Wp + 7168;
    const float* WintY = Wp + 7200;
    const float* WlY   = Wp + 11296;
    const float* btY   = Wp + 14368;

    const int nrx = (N + 31) / 32;
    const int nry = (E + 31) / 32;
    const int pull_gx = (N + 3) / 4;   // 4 waves/block, 1 row/wave
    const int pull_gy = (E + 3) / 4;
    const int nbs_g = (N + SCAN_CHUNK - 1) / SCAN_CHUNK;

    prep_k<<<16, 256, 0, stream>>>(th_mw, th_mb, th_lw, th_lb,
                                   ga_mw, ga_mb, ga_lw, ga_lb, Wp);
    hipMemsetAsync(stats, 0, 128 * sizeof(float), stream);
    hipMemsetAsync(counts_g, 0, (size_t)N * sizeof(int), stream);
    hipMemsetAsync(bcnt, 0, 1024 * sizeof(int), stream);

    // ---- CSR build: g (atomic path) ----
    hist_k<<<(E + 255) / 256, 256, 0, stream>>>(g_dst, E, counts_g);
    scan_block_k<<<nbs_g, 256, 0, stream>>>(counts_g, N, rowptr_g, bsums_g);
    scan_bsums_k<<<1, 256, 0, stream>>>(bsums_g, nbs_g);
    scan_add_k<<<(N + 255) / 256, 256, 0, stream>>>(rowptr_g, N, E, bsums_g);
    hipMemcpyAsync(counts_g, rowptr_g, (size_t)N * sizeof(int),
                   hipMemcpyDeviceToDevice, stream);
    scatter_g_k<<<(E + 255) / 256, 256, 0, stream>>>(g_src, g_dst, E,
                                                     counts_g, cs_g, ce_g);

    // ---- CSR build: lg (partitioned) ----
    bucket_hist_k<<<1024, 256, 0, stream>>>(lg_dst, LE, bcnt, nbuk);
    bucket_scan_k<<<1, 256, 0, stream>>>(bcnt, nbuk, LE, bstart, cursorA);
    partA_k<<<(LE + TILEE - 1) / TILEE, 256, 0, stream>>>(lg_src, lg_dst, LE,
                                                          cursorA, buf, nbuk);
    partB_k<<<nbuk, 256, 0, stream>>>(buf, bstart, E, LE, cs_lg, rowptr_lg);

    // ---------- x side ----------
    spmm_pull_k<<<pull_gx, 256, 0, stream>>>(y, ce_g, rowptr_g, pmpd, N);      // pmpd_y
    main_linear_k<<<nrx, 256, 0, stream>>>(x, deg_g, pmpd, nullptr, nullptr,
                                           WintX, btX, acc_x, N);
    spmm_pull_k<<<pull_gx, 256, 0, stream>>>(x, cs_g, rowptr_g, zA_x, N);      // h1
    accum_linear_k<<<nrx, 256, 0, stream>>>(zA_x, WlX, acc_x, N);
    spmm_pull_k<<<pull_gx, 256, 0, stream>>>(zA_x, cs_g, rowptr_g, zB_x, N);   // h2
    accum_linear_k<<<nrx, 256, 0, stream>>>(zB_x, WlX + 1024, acc_x, N);
    spmm_pull_k<<<pull_gx, 256, 0, stream>>>(zB_x, cs_g, rowptr_g, zA_x, N);   // h3
    spmm_pull_k<<<pull_gx, 256, 0, stream>>>(zA_x, cs_g, rowptr_g, zB_x, N);   // h4
    accum_linear_k<<<nrx, 256, 0, stream>>>(zB_x, WlX + 2048, acc_x, N);
    stats_relu_k<<<512, 256, 0, stream>>>(acc_x, N, stats);

    // ---------- y side ----------
    main_linear_k<<<nry, 256, 0, stream>>>(y, deg_lg, nullptr, x, pm_pd,
                                           WintY, btY, acc_y, E);
    spmm_pull_k<<<pull_gy, 256, 0, stream>>>(y, cs_lg, rowptr_lg, zA_y, E);    // h1
    accum_linear_k<<<nry, 256, 0, stream>>>(zA_y, WlY, acc_y, E);
    spmm_pull_k<<<pull_gy, 256, 0, stream>>>(zA_y, cs_lg, rowptr_lg, zB_y, E); // h2 (buf dead now)
    accum_linear_k<<<nry, 256, 0, stream>>>(zB_y, WlY + 1024, acc_y, E);
    spmm_pull_k<<<pull_gy, 256, 0, stream>>>(zB_y, cs_lg, rowptr_lg, zA_y, E); // h3
    spmm_pull_k<<<pull_gy, 256, 0, stream>>>(zA_y, cs_lg, rowptr_lg, zB_y, E); // h4
    accum_linear_k<<<nry, 256, 0, stream>>>(zB_y, WlY + 2048, acc_y, E);
    stats_relu_k<<<1024, 256, 0, stream>>>(acc_y, E, stats + 64);

    // ---------- BN fold + write ----------
    scalebias_k<<<1, 64, 0, stream>>>(stats, bn_x_sc, bn_x_bi, bn_y_sc, bn_y_bi,
                                      sb, N, E);
    finalize_k<<<(N * F + 255) / 256, 256, 0, stream>>>(acc_x, sb, out, N);
    finalize_k<<<(E * F + 255) / 256, 256, 0, stream>>>(acc_y, sb + 64,
                                                        out + (size_t)N * F, E);
}